// Round 4
// baseline (67713.342 us; speedup 1.0000x reference)
//
#include <hip/hip_runtime.h>
#include <hip/hip_bf16.h>
#include <math.h>

#define B_SZ 128
#define T_SZ 2048
#define NI 512
#define NH 512

// ---------------------------------------------------------------------------
// Kernel 1: x_proj = inputs @ W_xh + b_h, in-place into d_out's outs region.
// ~84% of fp32 VALU roofline -- unchanged since round 1.
// ---------------------------------------------------------------------------
#define BM 64
#define BN 64
#define BK 16

__global__ __launch_bounds__(256) void proj_gemm(
    const float* __restrict__ A,      // inputs [M=B*T, K=NI]
    const float* __restrict__ W,      // W_xh [K, N]
    const float* __restrict__ bias,   // b_h [N]
    float* __restrict__ C)            // d_out outs region [M, N]
{
    __shared__ float As[BK][BM];
    __shared__ float Bs[BK][BN];
    const int m0 = blockIdx.y * BM;
    const int n0 = blockIdx.x * BN;
    const int tid = threadIdx.x;
    const int tx = tid & 15;
    const int ty = tid >> 4;

    const int ar = tid >> 2;
    const int ac = (tid & 3) * 4;
    const int bk = tid >> 4;
    const int bn = (tid & 15) * 4;

    float acc[4][4] = {};

    for (int k0 = 0; k0 < NI; k0 += BK) {
        float4 av = *reinterpret_cast<const float4*>(
            &A[(size_t)(m0 + ar) * NI + k0 + ac]);
        float4 bv = *reinterpret_cast<const float4*>(
            &W[(size_t)(k0 + bk) * NH + n0 + bn]);
        __syncthreads();
        As[ac + 0][ar] = av.x;
        As[ac + 1][ar] = av.y;
        As[ac + 2][ar] = av.z;
        As[ac + 3][ar] = av.w;
        *reinterpret_cast<float4*>(&Bs[bk][bn]) = bv;
        __syncthreads();
        #pragma unroll
        for (int kk = 0; kk < BK; ++kk) {
            float a[4], b[4];
            #pragma unroll
            for (int i = 0; i < 4; ++i) a[i] = As[kk][ty * 4 + i];
            #pragma unroll
            for (int jj = 0; jj < 4; ++jj) b[jj] = Bs[kk][tx * 4 + jj];
            #pragma unroll
            for (int i = 0; i < 4; ++i)
                #pragma unroll
                for (int jj = 0; jj < 4; ++jj)
                    acc[i][jj] = fmaf(a[i], b[jj], acc[i][jj]);
        }
    }

    #pragma unroll
    for (int i = 0; i < 4; ++i) {
        const size_t row = (size_t)(m0 + ty * 4 + i);
        #pragma unroll
        for (int jj = 0; jj < 4; ++jj) {
            const int col = n0 + tx * 4 + jj;
            C[row * NH + col] = acc[i][jj] + bias[col];
        }
    }
}

// ---------------------------------------------------------------------------
// Kernel 2: persistent-weight scan, per-slice producer/consumer flags with
// RELEASE/ACQUIRE semantics (round-3's fully-relaxed protocol failed on HW:
// per-XCD L2s are non-coherent; the acquire-side buffer_inv is required so
// re-read hb lines aren't served stale from the local L2 — G16).
//
// 256 WGs x 512 thr, 1 WG/CU (LDS pad). WG (g,p): chains c0=4g..4g+3,
// columns j0=64p..64p+63. W slice (512x64) in VGPRs (launch_bounds(512,2)
// -> 256-VGPR cap; round-2's VGPR_Count=52 proved the default target spilled
// it to scratch -- this is the fix being tested).
//
// Per step t:
//   wave ks: ACQUIRE-spin on flag[g][ks] >= t  (acquire => buffer_inv, so
//            the following plain float4 loads of h_t chunk ks refetch fresh
//            data from the coherence point), stage into wave-private LDS;
//   dot over k-chunk for 4 chains; s1 barrier; waves 0..3 reduce + tanh,
//   NT-store to out, publish h_{t+1} via RELAXED sc1 atomic stores (bypass
//   L2 -> L2 stays clean, release wbl2 cheap); s2 barrier (per-wave vmcnt
//   drain; barrier gives happens-before transitivity to tid0); tid0 stores
//   flag=t+1 with RELEASE (the construct round 2 validated on HW).
//
// Overwrite safety (parity double-buffer): WG publishes h_{t+1} over h_{t-1}
// only after all its waves saw flags[g][*] >= t, i.e. every WG of the group
// finished its step-(t-1) reads of h_{t-1}. Parity-0 buffer == d_out's H_T
// region: h_2048 (t=2047 publish) lands there for free.
// ---------------------------------------------------------------------------
#define CPG 4        // chains per group
#define COLS 64      // columns per slice
#define SLICES 8
#define KCH 64       // k-chunk per wave (512/8)

__global__ __launch_bounds__(512, 2) void rnn_scan_p(
    const float* __restrict__ W,      // W_hh [512][512]
    const float* __restrict__ H0,     // [128][512]
    float* __restrict__ out,          // [128][2048][512]: xp on entry -> h
    float* __restrict__ hb0,          // parity-0 h buffer (== d_out hT region)
    float* __restrict__ hb1,          // parity-1 h buffer (in d_ws)
    unsigned int* __restrict__ flags) // [32*8] flags, stride 16 uints (64 B)
{
    __shared__ float h_lds[CPG][NH];             // 8 KB, wave-private chunks
    __shared__ float red_lds[SLICES][CPG][COLS]; // 8 KB
    __shared__ float lds_pad[18432];             // 72 KB: force 1 WG/CU

    const int tid = threadIdx.x;
    const int bid = blockIdx.x;
    const int g = bid & 31;          // chain-group
    const int p = bid >> 5;          // column-slice
    const int c0 = g * CPG;
    const int j0 = p * COLS;
    const int ks = tid >> 6;         // wave id = k-chunk index
    const int l  = tid & 63;         // lane

    if (bid == 0x7fffffff) lds_pad[tid] = 1.0f;  // keep pad allocated

    // --- W column-slice chunk -> VGPRs (once; coalesced 256B rows) ---
    float wr[KCH];
    {
        const float* wp = W + (size_t)(ks * KCH) * NH + j0 + l;
        #pragma unroll
        for (int e = 0; e < KCH; ++e)
            wr[e] = wp[(size_t)e * NH];
    }

    // --- stage h_0 chunk: lane l -> chain c=l>>4, float4 idx f=l&15 ---
    {
        const int c = l >> 4, f = l & 15;
        float4 v = *reinterpret_cast<const float4*>(
            H0 + (size_t)(c0 + c) * NH + ks * KCH + f * 4);
        *reinterpret_cast<float4*>(&h_lds[c][ks * KCH + f * 4]) = v;
    }

    // reduce-phase roles (threads 0..255 active)
    const int rc = tid >> 6;         // chain when < 4
    const int rj = tid & 63;
    float* outrow = out + (size_t)(c0 + (rc & 3)) * T_SZ * NH + j0 + rj;
    float xp_cur = (rc < CPG) ? outrow[0] : 0.f;

    unsigned int* flag_self = flags + (size_t)(g * SLICES + p) * 16;
    unsigned int* flag_src  = flags + (size_t)(g * SLICES + ks) * 16;

    for (int t = 0; t < T_SZ; ++t) {
        if (t > 0) {
            // ACQUIRE spin: each successful poll pairs with the producer's
            // RELEASE flag store -> h_t data visible to the loads below.
            while (__hip_atomic_load(flag_src, __ATOMIC_ACQUIRE,
                                     __HIP_MEMORY_SCOPE_AGENT) < (unsigned)t)
                __builtin_amdgcn_s_sleep(1);
            const float* hsrc = (t & 1) ? hb1 : hb0;
            const int c = l >> 4, f = l & 15;
            float4 v = *reinterpret_cast<const float4*>(
                hsrc + (size_t)(c0 + c) * NH + ks * KCH + f * 4);
            *reinterpret_cast<float4*>(&h_lds[c][ks * KCH + f * 4]) = v;
        }

        // prefetch next xp (hides HBM latency under the dot)
        float xp_next = 0.f;
        if (rc < CPG && t + 1 < T_SZ)
            xp_next = __builtin_nontemporal_load(outrow + (size_t)(t + 1) * NH);

        // --- dot: this wave's k-chunk, all 4 chains (wave-private LDS) ---
        float acc0 = 0.f, acc1 = 0.f, acc2 = 0.f, acc3 = 0.f;
        const float4* h0q = reinterpret_cast<const float4*>(&h_lds[0][0]);
        const float4* h1q = reinterpret_cast<const float4*>(&h_lds[1][0]);
        const float4* h2q = reinterpret_cast<const float4*>(&h_lds[2][0]);
        const float4* h3q = reinterpret_cast<const float4*>(&h_lds[3][0]);
        #pragma unroll
        for (int qq = 0; qq < 16; ++qq) {
            const int qi = ks * 16 + qq;
            float4 ha = h0q[qi];   // wave-uniform addr -> LDS broadcast
            float4 hb = h1q[qi];
            float4 hc = h2q[qi];
            float4 hd = h3q[qi];
            const float w0 = wr[qq * 4 + 0], w1 = wr[qq * 4 + 1];
            const float w2 = wr[qq * 4 + 2], w3 = wr[qq * 4 + 3];
            acc0 = fmaf(ha.w, w3, fmaf(ha.z, w2, fmaf(ha.y, w1, fmaf(ha.x, w0, acc0))));
            acc1 = fmaf(hb.w, w3, fmaf(hb.z, w2, fmaf(hb.y, w1, fmaf(hb.x, w0, acc1))));
            acc2 = fmaf(hc.w, w3, fmaf(hc.z, w2, fmaf(hc.y, w1, fmaf(hc.x, w0, acc2))));
            acc3 = fmaf(hd.w, w3, fmaf(hd.z, w2, fmaf(hd.y, w1, fmaf(hd.x, w0, acc3))));
        }
        red_lds[ks][0][l] = acc0;
        red_lds[ks][1][l] = acc1;
        red_lds[ks][2][l] = acc2;
        red_lds[ks][3][l] = acc3;
        __syncthreads();   // s1: partials visible

        // --- reduce + tanh + store + publish ---
        if (rc < CPG) {
            float s = red_lds[0][rc][rj];
            #pragma unroll
            for (int kk = 1; kk < SLICES; ++kk) s += red_lds[kk][rc][rj];
            const float hv = tanhf(xp_cur + s);
            __builtin_nontemporal_store(hv, outrow + (size_t)t * NH);
            float* hdst = ((t + 1) & 1) ? hb1 : hb0;
            __hip_atomic_store(
                (unsigned int*)&hdst[(size_t)(c0 + rc) * NH + j0 + rj],
                __float_as_uint(hv), __ATOMIC_RELAXED,
                __HIP_MEMORY_SCOPE_AGENT);   // sc1 direct -> L2 stays clean
            xp_cur = xp_next;
        }
        __syncthreads();   // s2: all waves' publishes drained (vmcnt0 + barrier)

        if (tid == 0)
            __hip_atomic_store(flag_self, (unsigned)(t + 1), __ATOMIC_RELEASE,
                               __HIP_MEMORY_SCOPE_AGENT);
    }
    // H_T: t=2047 publishes to parity 0 == hb0 == d_out's hT region.
}

// ---------------------------------------------------------------------------
extern "C" void kernel_launch(void* const* d_in, const int* in_sizes, int n_in,
                              void* d_out, int out_size, void* d_ws, size_t ws_size,
                              hipStream_t stream) {
    const float* inputs = (const float*)d_in[0];   // [B, T, NI]
    const float* H0     = (const float*)d_in[1];   // [B, NH]
    const float* W_xh   = (const float*)d_in[2];   // [NI, NH]
    const float* W_hh   = (const float*)d_in[3];   // [NH, NH]
    const float* b_h    = (const float*)d_in[4];   // [NH]

    float* out = (float*)d_out;                        // outs [B,T,NH]
    float* hT  = out + (size_t)B_SZ * T_SZ * NH;       // H_T [B,NH] == hb0

    unsigned int* flags = (unsigned int*)d_ws;         // 256 x 64 B flags
    float* hb1 = (float*)((char*)d_ws + 16384);        // 256 KB parity-1 buf

    // zero the flags each launch (graph-capture-safe, on stream)
    hipMemsetAsync(d_ws, 0, 16384, stream);

    // 1) input projection -> d_out outs region
    dim3 g1(NH / BN, (B_SZ * T_SZ) / BM);  // (8, 4096)
    proj_gemm<<<g1, 256, 0, stream>>>(inputs, W_xh, b_h, out);

    // 2) persistent recurrence: 256 WGs (32 chain-groups x 8 column-slices)
    rnn_scan_p<<<256, 512, 0, stream>>>(W_hh, H0, out, hT, hb1, flags);
}

// Round 5
// 15000.168 us; speedup vs baseline: 4.5142x; 4.5142x over previous
//
#include <hip/hip_runtime.h>
#include <hip/hip_bf16.h>
#include <math.h>

#define B_SZ 128
#define T_SZ 2048
#define NI 512
#define NH 512

// ---------------------------------------------------------------------------
// Kernel 0: pack W_hh into bf16-pair, k-blocked layout in d_ws.
//   wt3[kk4*512 + j] (uint4), dword q (0..3) = pack( bf16(W[8kk4+2q][j]),
//                                                    bf16(W[8kk4+2q+1][j]) )
// Scan-side: lane j loads uint4 at (kk4*512+j)*16B -> 64 lanes read 1 KB
// contiguous, perfectly coalesced; 512 KB total, L2-resident (shared by all
// WGs on an XCD).
// ---------------------------------------------------------------------------
__device__ __forceinline__ unsigned bf16_rne(float f) {
    unsigned u = __float_as_uint(f);
    return (u + 0x7fffu + ((u >> 16) & 1u)) >> 16;   // round-nearest-even
}

__global__ __launch_bounds__(256) void pack_whh(
    const float* __restrict__ W, uint4* __restrict__ wt3)
{
    const int idx = blockIdx.x * 256 + threadIdx.x;  // = kk4*512 + j
    const int j   = idx & 511;
    const int kk4 = idx >> 9;
    const int k0  = kk4 * 8;
    unsigned d[4];
    #pragma unroll
    for (int q = 0; q < 4; ++q) {
        const unsigned lo = bf16_rne(W[(size_t)(k0 + 2 * q)     * NH + j]);
        const unsigned hi = bf16_rne(W[(size_t)(k0 + 2 * q + 1) * NH + j]);
        d[q] = lo | (hi << 16);
    }
    wt3[idx] = make_uint4(d[0], d[1], d[2], d[3]);
}

// ---------------------------------------------------------------------------
// Kernel 1: x_proj = inputs @ W_xh + b_h, in-place into d_out's outs region.
// ~84% of fp32 VALU roofline -- unchanged since round 1.
// ---------------------------------------------------------------------------
#define BM 64
#define BN 64
#define BK 16

__global__ __launch_bounds__(256) void proj_gemm(
    const float* __restrict__ A,      // inputs [M=B*T, K=NI]
    const float* __restrict__ W,      // W_xh [K, N]
    const float* __restrict__ bias,   // b_h [N]
    float* __restrict__ C)            // d_out outs region [M, N]
{
    __shared__ float As[BK][BM];
    __shared__ float Bs[BK][BN];
    const int m0 = blockIdx.y * BM;
    const int n0 = blockIdx.x * BN;
    const int tid = threadIdx.x;
    const int tx = tid & 15;
    const int ty = tid >> 4;

    const int ar = tid >> 2;
    const int ac = (tid & 3) * 4;
    const int bk = tid >> 4;
    const int bn = (tid & 15) * 4;

    float acc[4][4] = {};

    for (int k0 = 0; k0 < NI; k0 += BK) {
        float4 av = *reinterpret_cast<const float4*>(
            &A[(size_t)(m0 + ar) * NI + k0 + ac]);
        float4 bv = *reinterpret_cast<const float4*>(
            &W[(size_t)(k0 + bk) * NH + n0 + bn]);
        __syncthreads();
        As[ac + 0][ar] = av.x;
        As[ac + 1][ar] = av.y;
        As[ac + 2][ar] = av.z;
        As[ac + 3][ar] = av.w;
        *reinterpret_cast<float4*>(&Bs[bk][bn]) = bv;
        __syncthreads();
        #pragma unroll
        for (int kk = 0; kk < BK; ++kk) {
            float a[4], b[4];
            #pragma unroll
            for (int i = 0; i < 4; ++i) a[i] = As[kk][ty * 4 + i];
            #pragma unroll
            for (int jj = 0; jj < 4; ++jj) b[jj] = Bs[kk][tx * 4 + jj];
            #pragma unroll
            for (int i = 0; i < 4; ++i)
                #pragma unroll
                for (int jj = 0; jj < 4; ++jj)
                    acc[i][jj] = fmaf(a[i], b[jj], acc[i][jj]);
        }
    }

    #pragma unroll
    for (int i = 0; i < 4; ++i) {
        const size_t row = (size_t)(m0 + ty * 4 + i);
        #pragma unroll
        for (int jj = 0; jj < 4; ++jj) {
            const int col = n0 + tx * 4 + jj;
            C[row * NH + col] = acc[i][jj] + bias[col];
        }
    }
}

// ---------------------------------------------------------------------------
// Kernel 2: ZERO-SYNC scan. One WG (512 thr) per chain, 128 WGs -> ~1 WG/CU.
// No cross-WG communication at all (no flags, no atomics, no deadlock/race
// surface). Thread j owns hidden unit j. Per step:
//   - stream this chain's full W_hh (bf16-packed, 512 KB) from L2 at the
//     per-CU fill rate (~135 GB/s -> ~3.8 us floor),
//   - h_t broadcast-read from LDS (wave-uniform float4 -> conflict-free),
//   - fp32 accumulate, tanh, write h to out (in-place over xp), ONE
//     __syncthreads per step (double-buffered h).
// xp_{t+1} prefetched nontemporally at step start (distinct address from the
// h_t store: position t+1 vs t -> in-place safe).
// ---------------------------------------------------------------------------
__global__ __launch_bounds__(512) void rnn_scan_z(
    const uint4* __restrict__ wt3,   // packed W_hh [64][512] uint4
    const float* __restrict__ H0,    // [128][512]
    float* __restrict__ out,         // [128][2048][512]: xp on entry -> h
    float* __restrict__ hT)          // [128][512]
{
    __shared__ float h[2][NH];       // 4 KB double buffer
    const int b = blockIdx.x;
    const int j = threadIdx.x;

    h[0][j] = H0[(size_t)b * NH + j];
    __syncthreads();

    float* outrow = out + (size_t)b * T_SZ * NH + j;
    float xp_cur = outrow[0];
    int cur = 0;
    float hv = 0.0f;

    const uint4* wrow = wt3 + j;     // + kk4*512 per k-block

    for (int t = 0; t < T_SZ; ++t) {
        const float xp_next = (t + 1 < T_SZ)
            ? __builtin_nontemporal_load(outrow + (size_t)(t + 1) * NH) : 0.0f;

        const float4* hq = reinterpret_cast<const float4*>(h[cur]);
        float acc = xp_cur;
        #pragma unroll 8
        for (int kk4 = 0; kk4 < 64; ++kk4) {
            const uint4 wv = wrow[kk4 * 512];        // 16B/lane, coalesced, L2-hit
            const float4 hA = hq[kk4 * 2];           // h[8kk4 .. +3]  (broadcast)
            const float4 hB = hq[kk4 * 2 + 1];       // h[8kk4+4 .. +7]
            acc = fmaf(hA.x, __uint_as_float(wv.x << 16),          acc);
            acc = fmaf(hA.y, __uint_as_float(wv.x & 0xffff0000u),  acc);
            acc = fmaf(hA.z, __uint_as_float(wv.y << 16),          acc);
            acc = fmaf(hA.w, __uint_as_float(wv.y & 0xffff0000u),  acc);
            acc = fmaf(hB.x, __uint_as_float(wv.z << 16),          acc);
            acc = fmaf(hB.y, __uint_as_float(wv.z & 0xffff0000u),  acc);
            acc = fmaf(hB.z, __uint_as_float(wv.w << 16),          acc);
            acc = fmaf(hB.w, __uint_as_float(wv.w & 0xffff0000u),  acc);
        }
        hv = tanhf(acc);
        __builtin_nontemporal_store(hv, outrow + (size_t)t * NH);
        h[cur ^ 1][j] = hv;
        __syncthreads();             // next-buffer complete before next dot
        cur ^= 1;
        xp_cur = xp_next;
    }
    hT[(size_t)b * NH + j] = hv;
}

// ---------------------------------------------------------------------------
extern "C" void kernel_launch(void* const* d_in, const int* in_sizes, int n_in,
                              void* d_out, int out_size, void* d_ws, size_t ws_size,
                              hipStream_t stream) {
    const float* inputs = (const float*)d_in[0];   // [B, T, NI]
    const float* H0     = (const float*)d_in[1];   // [B, NH]
    const float* W_xh   = (const float*)d_in[2];   // [NI, NH]
    const float* W_hh   = (const float*)d_in[3];   // [NH, NH]
    const float* b_h    = (const float*)d_in[4];   // [NH]

    float* out = (float*)d_out;                        // outs [B,T,NH]
    float* hT  = out + (size_t)B_SZ * T_SZ * NH;       // H_T [B,NH]

    uint4* wt3 = (uint4*)d_ws;                         // 512 KB packed W_hh

    // 0) pack W_hh -> bf16 pairs (deterministic, rewritten every launch)
    pack_whh<<<128, 256, 0, stream>>>(W_hh, wt3);

    // 1) input projection -> d_out outs region
    dim3 g1(NH / BN, (B_SZ * T_SZ) / BM);  // (8, 4096)
    proj_gemm<<<g1, 256, 0, stream>>>(inputs, W_xh, b_h, out);

    // 2) zero-sync recurrence: one WG per chain
    rnn_scan_z<<<128, 512, 0, stream>>>(wt3, H0, out, hT);
}

// Round 6
// 11338.491 us; speedup vs baseline: 5.9720x; 1.3229x over previous
//
#include <hip/hip_runtime.h>
#include <hip/hip_bf16.h>
#include <math.h>

#define B_SZ 128
#define T_SZ 2048
#define NI 512
#define NH 512

// ---------------------------------------------------------------------------
// Kernel 0: pack W_hh into bf16-pair, k-blocked layout in d_ws.
//   wt3[kk4*512 + j] (uint4), dword q (0..3) = pack( bf16(W[8kk4+2q][j]),
//                                                    bf16(W[8kk4+2q+1][j]) )
// Scan-side: lane j loads uint4 at (kk4*512+j)*16B -> 64 lanes read 1 KB
// contiguous, perfectly coalesced; 512 KB total, L2-resident.
// ---------------------------------------------------------------------------
__device__ __forceinline__ unsigned bf16_rne(float f) {
    unsigned u = __float_as_uint(f);
    return (u + 0x7fffu + ((u >> 16) & 1u)) >> 16;   // round-nearest-even
}

__global__ __launch_bounds__(256) void pack_whh(
    const float* __restrict__ W, uint4* __restrict__ wt3)
{
    const int idx = blockIdx.x * 256 + threadIdx.x;  // = kk4*512 + j
    const int j   = idx & 511;
    const int kk4 = idx >> 9;
    const int k0  = kk4 * 8;
    unsigned d[4];
    #pragma unroll
    for (int q = 0; q < 4; ++q) {
        const unsigned lo = bf16_rne(W[(size_t)(k0 + 2 * q)     * NH + j]);
        const unsigned hi = bf16_rne(W[(size_t)(k0 + 2 * q + 1) * NH + j]);
        d[q] = lo | (hi << 16);
    }
    wt3[idx] = make_uint4(d[0], d[1], d[2], d[3]);
}

// ---------------------------------------------------------------------------
// Kernel 1: x_proj = inputs @ W_xh + b_h, in-place into d_out's outs region.
// ~84% of fp32 VALU roofline -- unchanged since round 1.
// ---------------------------------------------------------------------------
#define BM 64
#define BN 64
#define BK 16

__global__ __launch_bounds__(256) void proj_gemm(
    const float* __restrict__ A,      // inputs [M=B*T, K=NI]
    const float* __restrict__ W,      // W_xh [K, N]
    const float* __restrict__ bias,   // b_h [N]
    float* __restrict__ C)            // d_out outs region [M, N]
{
    __shared__ float As[BK][BM];
    __shared__ float Bs[BK][BN];
    const int m0 = blockIdx.y * BM;
    const int n0 = blockIdx.x * BN;
    const int tid = threadIdx.x;
    const int tx = tid & 15;
    const int ty = tid >> 4;

    const int ar = tid >> 2;
    const int ac = (tid & 3) * 4;
    const int bk = tid >> 4;
    const int bn = (tid & 15) * 4;

    float acc[4][4] = {};

    for (int k0 = 0; k0 < NI; k0 += BK) {
        float4 av = *reinterpret_cast<const float4*>(
            &A[(size_t)(m0 + ar) * NI + k0 + ac]);
        float4 bv = *reinterpret_cast<const float4*>(
            &W[(size_t)(k0 + bk) * NH + n0 + bn]);
        __syncthreads();
        As[ac + 0][ar] = av.x;
        As[ac + 1][ar] = av.y;
        As[ac + 2][ar] = av.z;
        As[ac + 3][ar] = av.w;
        *reinterpret_cast<float4*>(&Bs[bk][bn]) = bv;
        __syncthreads();
        #pragma unroll
        for (int kk = 0; kk < BK; ++kk) {
            float a[4], b[4];
            #pragma unroll
            for (int i = 0; i < 4; ++i) a[i] = As[kk][ty * 4 + i];
            #pragma unroll
            for (int jj = 0; jj < 4; ++jj) b[jj] = Bs[kk][tx * 4 + jj];
            #pragma unroll
            for (int i = 0; i < 4; ++i)
                #pragma unroll
                for (int jj = 0; jj < 4; ++jj)
                    acc[i][jj] = fmaf(a[i], b[jj], acc[i][jj]);
        }
    }

    #pragma unroll
    for (int i = 0; i < 4; ++i) {
        const size_t row = (size_t)(m0 + ty * 4 + i);
        #pragma unroll
        for (int jj = 0; jj < 4; ++jj) {
            const int col = n0 + tx * 4 + jj;
            C[row * NH + col] = acc[i][jj] + bias[col];
        }
    }
}

// ---------------------------------------------------------------------------
// Kernel 2: ZERO-SYNC scan, 1024 threads/chain (16 waves = 4/SIMD for L2
// latency hiding; round-5's 8-wave version measured 6.7us/step ~= serial
// (3.4us W-stream + 2.1us VALU) -- not overlapped at 2 waves/SIMD).
// Thread t: column j=t&511, k-half=t>>9 (k in [256*half, 256*half+256)).
// Upper half writes its 256-k partial to ps[j]; lower half combines,
// tanh, stores h (in-place over xp) and the double-buffered LDS h.
// Hazards: ps write(t+1) is after s2(t), ps read(t) before s2(t) -- ordered.
// h[cur] reads(t) < s1(t) < s1(t+1) < h[cur] overwrite at t+1 -- ordered.
// ---------------------------------------------------------------------------
__global__ __launch_bounds__(1024, 4) void rnn_scan_z2(
    const uint4* __restrict__ wt3,   // packed W_hh [64][512] uint4
    const float* __restrict__ H0,    // [128][512]
    float* __restrict__ out,         // [128][2048][512]: xp on entry -> h
    float* __restrict__ hT)          // [128][512]
{
    __shared__ float h[2][NH];       // 4 KB double buffer
    __shared__ float ps[NH];         // 2 KB upper-half partials
    const int tid  = threadIdx.x;
    const int b    = blockIdx.x;
    const int j    = tid & 511;
    const int half = tid >> 9;       // 0: k 0..255, 1: k 256..511

    if (half == 0) h[0][j] = H0[(size_t)b * NH + j];
    __syncthreads();

    float* outrow = out + (size_t)b * T_SZ * NH + j;   // used by half 0 only
    float xp_cur = (half == 0) ? outrow[0] : 0.f;

    const uint4* wrow = wt3 + half * 32 * 512 + j;     // this half's k-blocks
    const int hq_base = half * 64;                     // float4 idx: half*256/4
    int cur = 0;
    float hv = 0.0f;

    for (int t = 0; t < T_SZ; ++t) {
        float xp_next = 0.f;
        if (half == 0 && t + 1 < T_SZ)
            xp_next = __builtin_nontemporal_load(outrow + (size_t)(t + 1) * NH);

        const float4* hq = reinterpret_cast<const float4*>(h[cur]) + hq_base;
        float acc = 0.0f;
        #pragma unroll 8
        for (int kk = 0; kk < 32; ++kk) {
            const uint4 wv = wrow[kk * 512];     // 16B/lane coalesced, L2-hit
            const float4 hA = hq[kk * 2];        // wave-uniform -> broadcast
            const float4 hB = hq[kk * 2 + 1];
            acc = fmaf(hA.x, __uint_as_float(wv.x << 16),          acc);
            acc = fmaf(hA.y, __uint_as_float(wv.x & 0xffff0000u),  acc);
            acc = fmaf(hA.z, __uint_as_float(wv.y << 16),          acc);
            acc = fmaf(hA.w, __uint_as_float(wv.y & 0xffff0000u),  acc);
            acc = fmaf(hB.x, __uint_as_float(wv.z << 16),          acc);
            acc = fmaf(hB.y, __uint_as_float(wv.z & 0xffff0000u),  acc);
            acc = fmaf(hB.z, __uint_as_float(wv.w << 16),          acc);
            acc = fmaf(hB.w, __uint_as_float(wv.w & 0xffff0000u),  acc);
        }
        if (half == 1) ps[j] = acc;
        __syncthreads();   // s1: partials visible
        if (half == 0) {
            hv = tanhf(acc + ps[j] + xp_cur);
            __builtin_nontemporal_store(hv, outrow + (size_t)t * NH);
            h[cur ^ 1][j] = hv;
            xp_cur = xp_next;
        }
        __syncthreads();   // s2: h[cur^1] complete before next dot
        cur ^= 1;
    }
    if (half == 0) hT[(size_t)b * NH + j] = hv;
}

// ---------------------------------------------------------------------------
extern "C" void kernel_launch(void* const* d_in, const int* in_sizes, int n_in,
                              void* d_out, int out_size, void* d_ws, size_t ws_size,
                              hipStream_t stream) {
    const float* inputs = (const float*)d_in[0];   // [B, T, NI]
    const float* H0     = (const float*)d_in[1];   // [B, NH]
    const float* W_xh   = (const float*)d_in[2];   // [NI, NH]
    const float* W_hh   = (const float*)d_in[3];   // [NH, NH]
    const float* b_h    = (const float*)d_in[4];   // [NH]

    float* out = (float*)d_out;                        // outs [B,T,NH]
    float* hT  = out + (size_t)B_SZ * T_SZ * NH;       // H_T [B,NH]

    uint4* wt3 = (uint4*)d_ws;                         // 512 KB packed W_hh

    // 0) pack W_hh -> bf16 pairs (deterministic, rewritten every launch)
    pack_whh<<<128, 256, 0, stream>>>(W_hh, wt3);

    // 1) input projection -> d_out outs region
    dim3 g1(NH / BN, (B_SZ * T_SZ) / BM);  // (8, 4096)
    proj_gemm<<<g1, 256, 0, stream>>>(inputs, W_xh, b_h, out);

    // 2) zero-sync recurrence: one 1024-thread WG per chain
    rnn_scan_z2<<<128, 1024, 0, stream>>>(wt3, H0, out, hT);
}